// Round 1
// baseline (1151.252 us; speedup 1.0000x reference)
//
#include <hip/hip_runtime.h>
#include <math.h>

// DynamicRouting: b=64, j=32, i=4096, n=16, iters=3 (hardcoded per setup_inputs)
// u_hat[b][j][i][n] fp32 (512 MB). Output: v2 [64,32,16] ++ entropy [64,3].
//
// Algebra: b_vec after iter k = u . (sum of v_t, t<=k)  (b_vec starts at 0),
// so iter1 logits = u.v0, iter2 logits = u.(v0+v1). Three passes over u_hat:
//   pass0: column sum -> s0 = (1/32) sum_i u   (c uniform, ent0 = ln 32)
//   pass1: fused  a=u.v0 -> softmax_j -> ent1, s1 = sum_i c1*u
//   pass2: fused  a=u.(v0+v1) -> softmax_j -> ent2, s2 = sum_i c2*u

#define WS_S0   0
#define WS_S1   32768
#define WS_S2   65536
#define WS_V0   98304
#define WS_W    131072
#define WS_ENT  163840      // 64*3 floats
#define WS_TOTAL 164032

// ---------------------------------------------------------------- pass 0
__global__ __launch_bounds__(256) void k_colsum(const float* __restrict__ u,
                                                float* __restrict__ s0) {
  const int bj = blockIdx.x;              // 0..2047  (b*32+j)
  const int t  = threadIdx.x;
  const int nq = t & 3;                   // float4 quadrant of n
  const int ir = t >> 2;                  // 0..63 row group
  const float4* base = (const float4*)u + (size_t)bj * 16384 + nq;
  float4 acc = make_float4(0.f, 0.f, 0.f, 0.f);
  #pragma unroll 8
  for (int ii = ir; ii < 4096; ii += 64) {
    const float4 x = base[(size_t)ii * 4];
    acc.x += x.x; acc.y += x.y; acc.z += x.z; acc.w += x.w;
  }
  __shared__ float4 red4[256];            // [ir][nq]
  red4[ir * 4 + nq] = acc;
  __syncthreads();
  if (t < 16) {
    const float* red = (const float*)red4;
    float s = 0.f;
    #pragma unroll
    for (int r = 0; r < 64; ++r) s += red[r * 16 + t];
    s0[bj * 16 + t] = s;
  }
}

// ---------------------------------------------------------------- squash helper
__device__ __forceinline__ void squash16(float* sb, const float* __restrict__ bias,
                                         int j, float* out16) {
  float ssum = 0.f;
  #pragma unroll
  for (int n = 0; n < 16; ++n) ssum += sb[n];
  if (ssum == 0.f) {                      // reference reset_mask: sum_n s == 0
    #pragma unroll
    for (int n = 0; n < 16; ++n) out16[n] = 0.f;
    return;
  }
  float sq = 0.f;
  #pragma unroll
  for (int n = 0; n < 16; ++n) { sb[n] += bias[j * 16 + n]; sq += sb[n] * sb[n]; }
  const float f = sq / ((1.f + sq) * sqrtf(sq + 1e-8f));
  #pragma unroll
  for (int n = 0; n < 16; ++n) out16[n] = sb[n] * f;
}

__global__ __launch_bounds__(256) void k_v0(const float* __restrict__ s0,
                                            const float* __restrict__ bias,
                                            float* __restrict__ v0) {
  const int bj = blockIdx.x * 256 + threadIdx.x;   // 2048 threads
  const int j = bj & 31;
  float sb[16], out[16];
  #pragma unroll
  for (int n = 0; n < 16; ++n) sb[n] = s0[bj * 16 + n] * (1.f / 32.f);
  squash16(sb, bias, j, out);
  #pragma unroll
  for (int n = 0; n < 16; ++n) v0[bj * 16 + n] = out[n];
}

__global__ __launch_bounds__(256) void k_v1(const float* __restrict__ s1,
                                            const float* __restrict__ bias,
                                            const float* __restrict__ v0,
                                            float* __restrict__ wv) {
  const int bj = blockIdx.x * 256 + threadIdx.x;
  const int j = bj & 31;
  float sb[16], out[16];
  #pragma unroll
  for (int n = 0; n < 16; ++n) sb[n] = s1[bj * 16 + n];
  squash16(sb, bias, j, out);
  #pragma unroll
  for (int n = 0; n < 16; ++n) wv[bj * 16 + n] = v0[bj * 16 + n] + out[n];  // v0+v1
}

__global__ __launch_bounds__(256) void k_final(const float* __restrict__ s2,
                                               const float* __restrict__ bias,
                                               const float* __restrict__ ent,
                                               float* __restrict__ out) {
  const int bj = blockIdx.x * 256 + threadIdx.x;
  const int j = bj & 31;
  float sb[16], v[16];
  #pragma unroll
  for (int n = 0; n < 16; ++n) sb[n] = s2[bj * 16 + n];
  squash16(sb, bias, j, v);
  float4* o4 = (float4*)(out + bj * 16);
  o4[0] = make_float4(v[0], v[1], v[2], v[3]);
  o4[1] = make_float4(v[4], v[5], v[6], v[7]);
  o4[2] = make_float4(v[8], v[9], v[10], v[11]);
  o4[3] = make_float4(v[12], v[13], v[14], v[15]);
  if (bj < 64) {                                   // entropy [b][3]
    out[32768 + bj * 3 + 0] = logf(32.f);          // uniform softmax entropy
    out[32768 + bj * 3 + 1] = ent[bj * 3 + 1] * (1.f / 4096.f);
    out[32768 + bj * 3 + 2] = ent[bj * 3 + 2] * (1.f / 4096.f);
  }
}

// ---------------------------------------------------------------- fused routing pass
// grid (32, 64): block = (i-chunk of 128, b). 8 sequential tiles of 16 i.
// LDS: u tile [32 j][16 i][16 n] = 32 KB + v 2 KB + a 2.2 KB + c 2 KB -> 4 blocks/CU.
__global__ __launch_bounds__(256) void k_route(const float* __restrict__ u,
                                               const float* __restrict__ vv,
                                               float* __restrict__ s_out,
                                               float* __restrict__ ent_ws,
                                               int iter) {
  const int b  = blockIdx.y;
  const int i0 = blockIdx.x * 128;
  const int t  = threadIdx.x;
  const int w  = t >> 6;                 // wave id 0..3
  const int ln = t & 63;
  const int li = ln >> 2;                // i within tile for staging
  const int lq = ln & 3;                 // n-quad for staging

  __shared__ float4 u_lds4[2048];        // [j][i][nq] = j*64 + i*4 + nq
  __shared__ float4 v_lds4[128];         // [j][nq]
  __shared__ float  a_lds[32 * 17];      // logits, padded stride 17
  __shared__ float  c_lds[32 * 16];      // routing coeffs
  float* u_lds = (float*)u_lds4;

  if (t < 128) v_lds4[t] = ((const float4*)vv)[b * 128 + t];

  // prefetch tile 0 into registers: 8 x float4 per thread (wave -> 1KB/j-row)
  const float4* ug = (const float4*)u;
  float4 r[8];
  #pragma unroll
  for (int L = 0; L < 8; ++L) {
    const int j = L * 4 + w;
    r[L] = ug[(size_t)(b * 32 + j) * 16384 + (size_t)(i0 + li) * 4 + lq];
  }

  const int jA  = t >> 3;                // j for phases A/B (0..31)
  const int i2  = t & 7;
  const int n0  = (t & 7) * 2;           // n pair for phase B
  const int d0  = jA & 1;                // lane-dependent i parity (bank spread)
  const int iiA = i2 * 2 + d0;
  const int iiB = i2 * 2 + 1 - d0;

  float acc0 = 0.f, acc1 = 0.f;          // s[j][n0], s[j][n0+1] partial over this block's i
  float ent_acc = 0.f;

  for (int tt = 0; tt < 8; ++tt) {
    __syncthreads();                     // prev tile's phase-B reads done (and v_lds on tt=0)
    #pragma unroll
    for (int L = 0; L < 8; ++L)
      u_lds4[(L * 4 + w) * 64 + ln] = r[L];
    __syncthreads();

    if (tt < 7) {                        // async prefetch next tile; consumed next iter
      #pragma unroll
      for (int L = 0; L < 8; ++L) {
        const int j = L * 4 + w;
        r[L] = ug[(size_t)(b * 32 + j) * 16384 + (size_t)(i0 + (tt + 1) * 16 + li) * 4 + lq];
      }
    }

    // phase A: logits a[j][i] = dot_n(u, v); 2 dots/thread, k-rotated for banks
    {
      float dA = 0.f, dB = 0.f;
      #pragma unroll
      for (int s = 0; s < 4; ++s) {
        const int k = (jA + i2 + s) & 3;
        const float4 vq = v_lds4[jA * 4 + k];
        const float4 xA = u_lds4[jA * 64 + iiA * 4 + k];
        const float4 xB = u_lds4[jA * 64 + iiB * 4 + k];
        dA += xA.x * vq.x + xA.y * vq.y + xA.z * vq.z + xA.w * vq.w;
        dB += xB.x * vq.x + xB.y * vq.y + xB.z * vq.z + xB.w * vq.w;
      }
      a_lds[jA * 17 + iiA] = dA;
      a_lds[jA * 17 + iiB] = dB;
    }
    __syncthreads();

    // softmax over j (16 lanes, one per i) + entropy: ent = logZ - sum c*(a-m)
    if (t < 16) {
      const int i = t;
      float m = -1e30f;
      #pragma unroll
      for (int j = 0; j < 32; ++j) m = fmaxf(m, a_lds[j * 17 + i]);
      float Z = 0.f, S = 0.f;
      #pragma unroll
      for (int j = 0; j < 32; ++j) {
        const float am = a_lds[j * 17 + i] - m;
        const float e = expf(am);
        Z += e; S += e * am;
        c_lds[j * 16 + i] = e;
      }
      const float rZ = 1.f / Z;
      #pragma unroll
      for (int j = 0; j < 32; ++j) c_lds[j * 16 + i] *= rZ;
      ent_acc += logf(Z) - S * rZ;
    }
    __syncthreads();

    // phase B: s[j][n] += c[j][i] * u[j][i][n], i-rotated for banks
    #pragma unroll
    for (int s = 0; s < 16; ++s) {
      const int i = (s + jA) & 15;
      const float c = c_lds[jA * 16 + i];
      const float2 x = *(const float2*)(u_lds + jA * 256 + i * 16 + n0);
      acc0 += c * x.x; acc1 += c * x.y;
    }
  }

  atomicAdd(&s_out[(b * 32 + jA) * 16 + n0],     acc0);
  atomicAdd(&s_out[(b * 32 + jA) * 16 + n0 + 1], acc1);

  if (t < 16) {                          // entropy block-reduce (lanes 0..15, wave 0)
    float e = ent_acc;
    e += __shfl_xor(e, 1);
    e += __shfl_xor(e, 2);
    e += __shfl_xor(e, 4);
    e += __shfl_xor(e, 8);
    if (t == 0) atomicAdd(&ent_ws[b * 3 + iter], e);
  }
}

extern "C" void kernel_launch(void* const* d_in, const int* in_sizes, int n_in,
                              void* d_out, int out_size, void* d_ws, size_t ws_size,
                              hipStream_t stream) {
  const float* u    = (const float*)d_in[0];
  const float* bias = (const float*)d_in[1];
  float* out = (float*)d_out;
  float* ws  = (float*)d_ws;

  hipMemsetAsync(d_ws, 0, WS_TOTAL * sizeof(float), stream);  // zero s1/s2/ent accumulators

  k_colsum<<<2048, 256, 0, stream>>>(u, ws + WS_S0);
  k_v0<<<8, 256, 0, stream>>>(ws + WS_S0, bias, ws + WS_V0);
  k_route<<<dim3(32, 64), 256, 0, stream>>>(u, ws + WS_V0, ws + WS_S1, ws + WS_ENT, 1);
  k_v1<<<8, 256, 0, stream>>>(ws + WS_S1, bias, ws + WS_V0, ws + WS_W);
  k_route<<<dim3(32, 64), 256, 0, stream>>>(u, ws + WS_W, ws + WS_S2, ws + WS_ENT, 2);
  k_final<<<8, 256, 0, stream>>>(ws + WS_S2, bias, ws + WS_ENT, out);
}

// Round 2
// 963.229 us; speedup vs baseline: 1.1952x; 1.1952x over previous
//
#include <hip/hip_runtime.h>
#include <hip/hip_fp16.h>
#include <math.h>

// DynamicRouting: b=64, j=32, i=4096, n=16, iters=3 (hardcoded per setup_inputs)
// u_hat[b][j][i][n] fp32 (512 MB). Output: v2 [64,32,16] ++ entropy [64,3].
//
// Algebra: b_vec after iter k = u.(sum of v_t, t<=k), so iter1 logits = u.v0,
// iter2 logits = u.(v0+v1). Pass 0 column-sums u AND writes an fp16 copy;
// passes 1-2 (fused logits+softmax+entropy+weighted-sum) read the fp16 copy.
// Traffic: 512R + 256W + 2x256R = 1.28 GB  (~200 us at 6.3 TB/s).

#define WS_S0   0
#define WS_S1   32768
#define WS_S2   65536
#define WS_V0   98304
#define WS_W    131072
#define WS_ENT  163840      // 64*3 floats
#define WS_TOTAL 164032
#define WS_U16  262144      // float offset (byte 1 MB): fp16 u copy, 256 MB

union H2U { unsigned u; __half2 h; };

// ---------------------------------------------------------------- pass 0
// Column sum over i AND fp16 compression. 2048 blocks (b*j), 256 thr.
__global__ __launch_bounds__(256) void k_colsum(const float* __restrict__ u,
                                                __half* __restrict__ u16,
                                                float* __restrict__ s0) {
  const int bj = blockIdx.x;
  const int t  = threadIdx.x;
  const float4* base = (const float4*)u + (size_t)bj * 16384;
  uint2* out = (uint2*)u16 + (size_t)bj * 16384;    // 4 halfs per float4
  float4 acc = make_float4(0.f, 0.f, 0.f, 0.f);
  #pragma unroll 4
  for (int k = 0; k < 64; ++k) {
    const int idx = t + k * 256;                    // nq = t&3 invariant
    const float4 x = base[idx];
    acc.x += x.x; acc.y += x.y; acc.z += x.z; acc.w += x.w;
    H2U p0, p1;
    p0.h = __float22half2_rn(make_float2(x.x, x.y));
    p1.h = __float22half2_rn(make_float2(x.z, x.w));
    out[idx] = make_uint2(p0.u, p1.u);
  }
  __shared__ float4 red4[256];
  red4[t] = acc;
  __syncthreads();
  if (t < 16) {
    const float* red = (const float*)red4;
    float s = 0.f;
    #pragma unroll
    for (int r = 0; r < 64; ++r) s += red[r * 16 + t];
    s0[bj * 16 + t] = s;
  }
}

// ---------------------------------------------------------------- squash helper
__device__ __forceinline__ void squash16(float* sb, const float* __restrict__ bias,
                                         int j, float* out16) {
  float ssum = 0.f;
  #pragma unroll
  for (int n = 0; n < 16; ++n) ssum += sb[n];
  if (ssum == 0.f) {                      // reference reset_mask: sum_n s == 0
    #pragma unroll
    for (int n = 0; n < 16; ++n) out16[n] = 0.f;
    return;
  }
  float sq = 0.f;
  #pragma unroll
  for (int n = 0; n < 16; ++n) { sb[n] += bias[j * 16 + n]; sq += sb[n] * sb[n]; }
  const float f = sq / ((1.f + sq) * sqrtf(sq + 1e-8f));
  #pragma unroll
  for (int n = 0; n < 16; ++n) out16[n] = sb[n] * f;
}

__global__ __launch_bounds__(256) void k_v0(const float* __restrict__ s0,
                                            const float* __restrict__ bias,
                                            float* __restrict__ v0) {
  const int bj = blockIdx.x * 256 + threadIdx.x;
  const int j = bj & 31;
  float sb[16], out[16];
  #pragma unroll
  for (int n = 0; n < 16; ++n) sb[n] = s0[bj * 16 + n] * (1.f / 32.f);
  squash16(sb, bias, j, out);
  #pragma unroll
  for (int n = 0; n < 16; ++n) v0[bj * 16 + n] = out[n];
}

__global__ __launch_bounds__(256) void k_v1(const float* __restrict__ s1,
                                            const float* __restrict__ bias,
                                            const float* __restrict__ v0,
                                            float* __restrict__ wv) {
  const int bj = blockIdx.x * 256 + threadIdx.x;
  const int j = bj & 31;
  float sb[16], out[16];
  #pragma unroll
  for (int n = 0; n < 16; ++n) sb[n] = s1[bj * 16 + n];
  squash16(sb, bias, j, out);
  #pragma unroll
  for (int n = 0; n < 16; ++n) wv[bj * 16 + n] = v0[bj * 16 + n] + out[n];  // v0+v1
}

__global__ __launch_bounds__(256) void k_final(const float* __restrict__ s2,
                                               const float* __restrict__ bias,
                                               const float* __restrict__ ent,
                                               float* __restrict__ out) {
  const int bj = blockIdx.x * 256 + threadIdx.x;
  const int j = bj & 31;
  float sb[16], v[16];
  #pragma unroll
  for (int n = 0; n < 16; ++n) sb[n] = s2[bj * 16 + n];
  squash16(sb, bias, j, v);
  float4* o4 = (float4*)(out + bj * 16);
  o4[0] = make_float4(v[0], v[1], v[2], v[3]);
  o4[1] = make_float4(v[4], v[5], v[6], v[7]);
  o4[2] = make_float4(v[8], v[9], v[10], v[11]);
  o4[3] = make_float4(v[12], v[13], v[14], v[15]);
  if (bj < 64) {                                   // entropy [b][3]
    out[32768 + bj * 3 + 0] = logf(32.f);          // uniform softmax entropy
    out[32768 + bj * 3 + 1] = ent[bj * 3 + 1] * (1.f / 4096.f);
    out[32768 + bj * 3 + 2] = ent[bj * 3 + 2] * (1.f / 4096.f);
  }
}

// ---------------------------------------------------------------- fused routing pass
// grid (16, 64): block = (256-i chunk, b). 8 tiles of 32 i, fp16 LDS.
// Thread (grp = t>>5, j = t&31): softmax over j = width-32 in-wave shuffles.
// Per-thread register accumulation of s[j][0..15]; one LDS reduce at the end.
__global__ __launch_bounds__(256) void k_route(const __half* __restrict__ u16,
                                               const float* __restrict__ vv,
                                               float* __restrict__ s_out,
                                               float* __restrict__ ent_ws,
                                               int iter) {
  const int b  = blockIdx.y;
  const int i0 = blockIdx.x * 256;
  const int t  = threadIdx.x;
  const int w  = t >> 6;                 // wave 0..3
  const int ln = t & 63;
  const int jl = t & 31;                 // j for compute
  const int grp = t >> 5;                // i-slot group 0..7

  // LDS: u tile [32 j][32 i][16 n] fp16, row stride 1024+16 B (bank pad).
  __shared__ __align__(16) unsigned char u_raw[32 * 1040];
  __shared__ float v_l[512];

  if (t < 128) ((float4*)v_l)[t] = ((const float4*)vv)[b * 128 + t];
  __syncthreads();
  float vr[16];
  #pragma unroll
  for (int n = 0; n < 16; ++n) vr[n] = v_l[jl * 16 + n];

  // global: uint4 = 8 halfs; one j-row of the tile = 64 uint4 (1 KB)
  const uint4* gbase = (const uint4*)u16 + (size_t)(b * 32) * 8192;
  uint4 r[8];
  #pragma unroll
  for (int L = 0; L < 8; ++L)
    r[L] = gbase[(size_t)(L * 4 + w) * 8192 + (size_t)i0 * 2 + ln];

  float acc[16];
  #pragma unroll
  for (int n = 0; n < 16; ++n) acc[n] = 0.f;
  float ent_acc = 0.f;

  for (int tt = 0; tt < 8; ++tt) {
    __syncthreads();                     // prev tile's reads done
    #pragma unroll
    for (int L = 0; L < 8; ++L)
      *(uint4*)(u_raw + (L * 4 + w) * 1040 + ln * 16) = r[L];
    __syncthreads();

    if (tt < 7) {                        // prefetch next tile
      #pragma unroll
      for (int L = 0; L < 8; ++L)
        r[L] = gbase[(size_t)(L * 4 + w) * 8192 + (size_t)(i0 + (tt + 1) * 32) * 2 + ln];
    }

    #pragma unroll
    for (int q = 0; q < 4; ++q) {
      const int il = grp * 4 + q;        // i within tile; uniform across 32-lane group
      const unsigned char* row = u_raw + jl * 1040 + il * 32;
      const uint4 da = *(const uint4*)(row);
      const uint4 db = *(const uint4*)(row + 16);
      float f[16];
      {
        H2U h; float2 p;
        h.u = da.x; p = __half22float2(h.h); f[0] = p.x;  f[1] = p.y;
        h.u = da.y; p = __half22float2(h.h); f[2] = p.x;  f[3] = p.y;
        h.u = da.z; p = __half22float2(h.h); f[4] = p.x;  f[5] = p.y;
        h.u = da.w; p = __half22float2(h.h); f[6] = p.x;  f[7] = p.y;
        h.u = db.x; p = __half22float2(h.h); f[8] = p.x;  f[9] = p.y;
        h.u = db.y; p = __half22float2(h.h); f[10] = p.x; f[11] = p.y;
        h.u = db.z; p = __half22float2(h.h); f[12] = p.x; f[13] = p.y;
        h.u = db.w; p = __half22float2(h.h); f[14] = p.x; f[15] = p.y;
      }
      float a = 0.f;
      #pragma unroll
      for (int n = 0; n < 16; ++n) a += f[n] * vr[n];

      // softmax over j: width-32 butterfly (lanes 0-31 / 32-63 independent)
      float m = a;
      #pragma unroll
      for (int msk = 16; msk >= 1; msk >>= 1) m = fmaxf(m, __shfl_xor(m, msk, 32));
      const float e = expf(a - m);
      float Z = e, S = e * (a - m);
      #pragma unroll
      for (int msk = 16; msk >= 1; msk >>= 1) {
        Z += __shfl_xor(Z, msk, 32);
        S += __shfl_xor(S, msk, 32);
      }
      const float rZ = 1.f / Z;
      const float c = e * rZ;
      ent_acc += logf(Z) - S * rZ;       // identical across the 32-lane group
      #pragma unroll
      for (int n = 0; n < 16; ++n) acc[n] += c * f[n];
    }
  }

  // block reduce: acc over the 8 grp slots, via padded LDS (reuse u tile)
  __syncthreads();
  float* red = (float*)u_raw;            // 8*32*17 floats = 17.4 KB <= 33.3 KB
  #pragma unroll
  for (int n = 0; n < 16; ++n) red[(grp * 32 + jl) * 17 + n] = acc[n];
  __syncthreads();
  const int jo = t >> 3, np = t & 7;
  float s0v = 0.f, s1v = 0.f;
  #pragma unroll
  for (int g = 0; g < 8; ++g) {
    s0v += red[(g * 32 + jo) * 17 + np * 2];
    s1v += red[(g * 32 + jo) * 17 + np * 2 + 1];
  }
  atomicAdd(&s_out[(b * 32 + jo) * 16 + np * 2],     s0v);
  atomicAdd(&s_out[(b * 32 + jo) * 16 + np * 2 + 1], s1v);

  float e = ent_acc;                     // per-group value; combine the wave's 2 groups
  e += __shfl_xor(e, 32);
  if (ln == 0) atomicAdd(&ent_ws[b * 3 + iter], e);
}

extern "C" void kernel_launch(void* const* d_in, const int* in_sizes, int n_in,
                              void* d_out, int out_size, void* d_ws, size_t ws_size,
                              hipStream_t stream) {
  const float* u    = (const float*)d_in[0];
  const float* bias = (const float*)d_in[1];
  float* out = (float*)d_out;
  float* ws  = (float*)d_ws;
  __half* u16 = (__half*)(ws + WS_U16);

  hipMemsetAsync(d_ws, 0, WS_TOTAL * sizeof(float), stream);  // zero s1/s2/ent

  k_colsum<<<2048, 256, 0, stream>>>(u, u16, ws + WS_S0);
  k_v0<<<8, 256, 0, stream>>>(ws + WS_S0, bias, ws + WS_V0);
  k_route<<<dim3(16, 64), 256, 0, stream>>>(u16, ws + WS_V0, ws + WS_S1, ws + WS_ENT, 1);
  k_v1<<<8, 256, 0, stream>>>(ws + WS_S1, bias, ws + WS_V0, ws + WS_W);
  k_route<<<dim3(16, 64), 256, 0, stream>>>(u16, ws + WS_W, ws + WS_S2, ws + WS_ENT, 2);
  k_final<<<8, 256, 0, stream>>>(ws + WS_S2, bias, ws + WS_ENT, out);
}

// Round 3
// 803.208 us; speedup vs baseline: 1.4333x; 1.1992x over previous
//
#include <hip/hip_runtime.h>
#include <hip/hip_fp16.h>
#include <math.h>

// DynamicRouting: b=64, j=32, i=4096, n=16, iters=3 (hardcoded per setup_inputs)
// u_hat[b][j][i][n] fp32 (512 MB). Output: v2 [64,32,16] ++ entropy [64,3].
//
// Algebra: b_vec after iter k = u.(sum of v_t, t<=k): iter1 logits = u.v0,
// iter2 logits = u.(v0+v1). Pass 0 column-sums u (non-temporal fp32 reads, so
// the fp16 copy it writes stays L3-resident) ; passes 1-2 are fused
// logits+softmax+entropy+weighted-sum over the fp16 copy, recomputing the
// tiny squash(v) in-block from s0/s1 (no separate small kernels).
// HBM floor: 512R + 256W(+flush) ; route reads mostly L3.

#define WS_S0   0           // 2048*16 floats, plain store (no zeroing needed)
#define WS_S1   32768
#define WS_S2   65536
#define WS_ENT  98304       // 64*3 floats
#define WS_ZERO_FLOATS (65536 + 192)          // s1+s2+ent
#define WS_U16  262144      // float offset (byte 1 MB): fp16 u copy, 256 MB

typedef float  f4v __attribute__((ext_vector_type(4)));
typedef unsigned u4v __attribute__((ext_vector_type(4)));

union H2U { unsigned u; __half2 h; };

// ---------------------------------------------------------------- pass 0
// Column sum over i AND fp16 compression. 2048 blocks (b*j), 256 thr.
// fp32 reads are non-temporal: single-use stream, keep L3 for u16.
__global__ __launch_bounds__(256) void k_colsum(const float* __restrict__ u,
                                                __half* __restrict__ u16,
                                                float* __restrict__ s0) {
  const int bj = blockIdx.x;
  const int t  = threadIdx.x;
  const f4v* base = (const f4v*)u + (size_t)bj * 16384;
  uint2* out = (uint2*)u16 + (size_t)bj * 16384;    // 4 halfs per float4
  f4v acc = {0.f, 0.f, 0.f, 0.f};
  #pragma unroll 4
  for (int k = 0; k < 64; ++k) {
    const int idx = t + k * 256;                    // nq = t&3 invariant
    const f4v x = __builtin_nontemporal_load(base + idx);
    acc += x;
    H2U p0, p1;
    p0.h = __float22half2_rn(make_float2(x.x, x.y));
    p1.h = __float22half2_rn(make_float2(x.z, x.w));
    out[idx] = make_uint2(p0.u, p1.u);
  }
  __shared__ f4v red4[256];
  red4[t] = acc;
  __syncthreads();
  if (t < 16) {
    const float* red = (const float*)red4;
    float s = 0.f;
    #pragma unroll
    for (int r = 0; r < 64; ++r) s += red[r * 16 + t];
    s0[bj * 16 + t] = s;
  }
}

// ---------------------------------------------------------------- squash helper
__device__ __forceinline__ void squash16(float* sb, const float* __restrict__ bias,
                                         int j, float* out16) {
  float ssum = 0.f;
  #pragma unroll
  for (int n = 0; n < 16; ++n) ssum += sb[n];
  if (ssum == 0.f) {                      // reference reset_mask: sum_n s == 0
    #pragma unroll
    for (int n = 0; n < 16; ++n) out16[n] = 0.f;
    return;
  }
  float sq = 0.f;
  #pragma unroll
  for (int n = 0; n < 16; ++n) { sb[n] += bias[j * 16 + n]; sq += sb[n] * sb[n]; }
  const float f = sq / ((1.f + sq) * sqrtf(sq + 1e-8f));
  #pragma unroll
  for (int n = 0; n < 16; ++n) out16[n] = sb[n] * f;
}

// ---------------------------------------------------------------- fused routing pass
// grid (16, 64): block = (256-i chunk, b). 8 tiles of 32 i, fp16 LDS.
// v recomputed in-block from s0 (and s1 for pass 2) — no tiny kernels between.
// Thread (grp = t>>5, j = t&31): softmax over j = width-32 in-wave shuffles.
__global__ __launch_bounds__(256) void k_route(const __half* __restrict__ u16,
                                               const float* __restrict__ s0,
                                               const float* __restrict__ s1,  // null for pass 1
                                               const float* __restrict__ bias,
                                               float* __restrict__ s_out,
                                               float* __restrict__ ent_ws,
                                               int iter, int last) {
  const int b  = blockIdx.y;
  const int i0 = blockIdx.x * 256;
  const int t  = threadIdx.x;
  const int w  = t >> 6;                 // wave 0..3
  const int ln = t & 63;
  const int jl = t & 31;                 // j for compute
  const int grp = t >> 5;                // i-slot group 0..7

  // LDS: u tile [32 j][32 i][16 n] fp16, row stride 1024+16 B (bank pad).
  __shared__ __align__(16) unsigned char u_raw[32 * 1040];
  __shared__ float v_l[512];

  // global prefetch tile 0: uint4 = 8 halfs; one j-row of tile = 64 uint4 (1 KB)
  const u4v* gbase = (const u4v*)u16 + (size_t)(b * 32) * 8192;
  u4v r[8];
  #pragma unroll
  for (int L = 0; L < 8; ++L)
    r[L] = last ? __builtin_nontemporal_load(gbase + (size_t)(L * 4 + w) * 8192 + (size_t)i0 * 2 + ln)
                : gbase[(size_t)(L * 4 + w) * 8192 + (size_t)i0 * 2 + ln];

  // in-block v: v0 = squash(s0/32); pass2 adds v1 = squash(s1)
  if (t < 32) {
    const int j = t;
    float sb[16], vout[16];
    #pragma unroll
    for (int n = 0; n < 16; ++n) sb[n] = s0[b * 512 + j * 16 + n] * (1.f / 32.f);
    squash16(sb, bias, j, vout);
    if (s1 != nullptr) {
      float sb1[16], v1[16];
      #pragma unroll
      for (int n = 0; n < 16; ++n) sb1[n] = s1[b * 512 + j * 16 + n];
      squash16(sb1, bias, j, v1);
      #pragma unroll
      for (int n = 0; n < 16; ++n) vout[n] += v1[n];
    }
    #pragma unroll
    for (int n = 0; n < 16; ++n) v_l[j * 16 + n] = vout[n];
  }
  __syncthreads();
  float vr[16];
  #pragma unroll
  for (int n = 0; n < 16; ++n) vr[n] = v_l[jl * 16 + n];

  float acc[16];
  #pragma unroll
  for (int n = 0; n < 16; ++n) acc[n] = 0.f;
  float ent_acc = 0.f;

  for (int tt = 0; tt < 8; ++tt) {
    __syncthreads();                     // prev tile's reads done
    #pragma unroll
    for (int L = 0; L < 8; ++L)
      *(u4v*)(u_raw + (L * 4 + w) * 1040 + ln * 16) = r[L];
    __syncthreads();

    if (tt < 7) {                        // prefetch next tile
      #pragma unroll
      for (int L = 0; L < 8; ++L) {
        const size_t gi = (size_t)(L * 4 + w) * 8192 + (size_t)(i0 + (tt + 1) * 32) * 2 + ln;
        r[L] = last ? __builtin_nontemporal_load(gbase + gi) : gbase[gi];
      }
    }

    #pragma unroll
    for (int q = 0; q < 4; ++q) {
      const int il = grp * 4 + q;        // i within tile; uniform across 32-lane group
      const unsigned char* row = u_raw + jl * 1040 + il * 32;
      const u4v da = *(const u4v*)(row);
      const u4v db = *(const u4v*)(row + 16);
      float f[16];
      {
        H2U h; float2 p;
        h.u = da.x; p = __half22float2(h.h); f[0] = p.x;  f[1] = p.y;
        h.u = da.y; p = __half22float2(h.h); f[2] = p.x;  f[3] = p.y;
        h.u = da.z; p = __half22float2(h.h); f[4] = p.x;  f[5] = p.y;
        h.u = da.w; p = __half22float2(h.h); f[6] = p.x;  f[7] = p.y;
        h.u = db.x; p = __half22float2(h.h); f[8] = p.x;  f[9] = p.y;
        h.u = db.y; p = __half22float2(h.h); f[10] = p.x; f[11] = p.y;
        h.u = db.z; p = __half22float2(h.h); f[12] = p.x; f[13] = p.y;
        h.u = db.w; p = __half22float2(h.h); f[14] = p.x; f[15] = p.y;
      }
      float a = 0.f;
      #pragma unroll
      for (int n = 0; n < 16; ++n) a += f[n] * vr[n];

      // softmax over j: width-32 butterfly (lanes 0-31 / 32-63 independent)
      float m = a;
      #pragma unroll
      for (int msk = 16; msk >= 1; msk >>= 1) m = fmaxf(m, __shfl_xor(m, msk, 32));
      const float e = expf(a - m);
      float Z = e, S = e * (a - m);
      #pragma unroll
      for (int msk = 16; msk >= 1; msk >>= 1) {
        Z += __shfl_xor(Z, msk, 32);
        S += __shfl_xor(S, msk, 32);
      }
      const float rZ = 1.f / Z;
      const float c = e * rZ;
      ent_acc += logf(Z) - S * rZ;       // identical across the 32-lane group
      #pragma unroll
      for (int n = 0; n < 16; ++n) acc[n] += c * f[n];
    }
  }

  // block reduce: acc over the 8 grp slots, via padded LDS (reuse u tile)
  __syncthreads();
  float* red = (float*)u_raw;            // 8*32*17 floats = 17.4 KB <= 33.3 KB
  #pragma unroll
  for (int n = 0; n < 16; ++n) red[(grp * 32 + jl) * 17 + n] = acc[n];
  __syncthreads();
  const int jo = t >> 3, np = t & 7;
  float s0v = 0.f, s1v = 0.f;
  #pragma unroll
  for (int g = 0; g < 8; ++g) {
    s0v += red[(g * 32 + jo) * 17 + np * 2];
    s1v += red[(g * 32 + jo) * 17 + np * 2 + 1];
  }
  atomicAdd(&s_out[(b * 32 + jo) * 16 + np * 2],     s0v);
  atomicAdd(&s_out[(b * 32 + jo) * 16 + np * 2 + 1], s1v);

  float e = ent_acc;                     // per-group value; combine the wave's 2 groups
  e += __shfl_xor(e, 32);
  if (ln == 0) atomicAdd(&ent_ws[b * 3 + iter], e);
}

// ---------------------------------------------------------------- epilogue
__global__ __launch_bounds__(256) void k_final(const float* __restrict__ s2,
                                               const float* __restrict__ bias,
                                               const float* __restrict__ ent,
                                               float* __restrict__ out) {
  const int bj = blockIdx.x * 256 + threadIdx.x;   // 2048 threads
  const int j = bj & 31;
  float sb[16], v[16];
  #pragma unroll
  for (int n = 0; n < 16; ++n) sb[n] = s2[bj * 16 + n];
  squash16(sb, bias, j, v);
  float4* o4 = (float4*)(out + bj * 16);
  o4[0] = make_float4(v[0], v[1], v[2], v[3]);
  o4[1] = make_float4(v[4], v[5], v[6], v[7]);
  o4[2] = make_float4(v[8], v[9], v[10], v[11]);
  o4[3] = make_float4(v[12], v[13], v[14], v[15]);
  if (bj < 64) {                                   // entropy [b][3]
    out[32768 + bj * 3 + 0] = logf(32.f);          // uniform softmax entropy
    out[32768 + bj * 3 + 1] = ent[bj * 3 + 1] * (1.f / 4096.f);
    out[32768 + bj * 3 + 2] = ent[bj * 3 + 2] * (1.f / 4096.f);
  }
}

extern "C" void kernel_launch(void* const* d_in, const int* in_sizes, int n_in,
                              void* d_out, int out_size, void* d_ws, size_t ws_size,
                              hipStream_t stream) {
  const float* u    = (const float*)d_in[0];
  const float* bias = (const float*)d_in[1];
  float* out = (float*)d_out;
  float* ws  = (float*)d_ws;
  __half* u16 = (__half*)(ws + WS_U16);

  // zero only s1/s2/ent (atomic accumulators)
  hipMemsetAsync(ws + WS_S1, 0, WS_ZERO_FLOATS * sizeof(float), stream);

  k_colsum<<<2048, 256, 0, stream>>>(u, u16, ws + WS_S0);
  k_route<<<dim3(16, 64), 256, 0, stream>>>(u16, ws + WS_S0, nullptr, bias,
                                            ws + WS_S1, ws + WS_ENT, 1, 0);
  k_route<<<dim3(16, 64), 256, 0, stream>>>(u16, ws + WS_S0, ws + WS_S1, bias,
                                            ws + WS_S2, ws + WS_ENT, 2, 1);
  k_final<<<8, 256, 0, stream>>>(ws + WS_S2, bias, ws + WS_ENT, out);
}